// Round 1
// baseline (181.907 us; speedup 1.0000x reference)
//
#include <hip/hip_runtime.h>

// QIntSoftmax: out = exp_int / sum(exp_int) with I-BERT integer softmax.
// x: (B=8, H=12, S=1024, S=1024) fp32, scales: (H,) fp32, out: same shape fp32.
// One 256-thread block per row of 1024 elements; float4 loads; values kept in
// registers across the max-reduce -> poly -> sum-reduce -> normalize pipeline.

constexpr int SROW = 1024;

__device__ __forceinline__ float wave_reduce_max(float v) {
#pragma unroll
  for (int off = 32; off > 0; off >>= 1)
    v = fmaxf(v, __shfl_xor(v, off));
  return v;
}

__device__ __forceinline__ float wave_reduce_sum(float v) {
#pragma unroll
  for (int off = 32; off > 0; off >>= 1)
    v += __shfl_xor(v, off);
  return v;
}

__global__ __launch_bounds__(256) void qint_softmax_kernel(
    const float* __restrict__ x, const float* __restrict__ scales,
    float* __restrict__ out, int H) {
  const int row = blockIdx.x;                 // row in [0, B*H*S)
  const int h = (row >> 10) % H;              // head index (S == 1024)
  const float s = scales[h];

  // Per-head constants, mirroring JAX weak-type promotion:
  // python-double constant -> f32, then correctly-rounded f32 division.
  const float x0_int = floorf(-0.6931f / s);
  const float b_int  = floorf((float)(0.96963238 / 0.35815147) / s);
  const float c_int  = floorf((float)(1.0 / 0.35815147) / (s * s));
  const float clampv = 30.0f * x0_int;        // N_BITS * x0_int (exact)

  const int tid = threadIdx.x;
  const float4 v = reinterpret_cast<const float4*>(x + (size_t)row * SROW)[tid];

  // x_int = x / s  (real IEEE div so floor boundaries match the reference)
  const float xi0 = v.x / s;
  const float xi1 = v.y / s;
  const float xi2 = v.z / s;
  const float xi3 = v.w / s;

  __shared__ float redm[4], reds[4];
  const int wave = tid >> 6;

  // ---- row max ----
  float m = wave_reduce_max(fmaxf(fmaxf(xi0, xi1), fmaxf(xi2, xi3)));
  if ((tid & 63) == 0) redm[wave] = m;
  __syncthreads();
  m = fmaxf(fmaxf(redm[0], redm[1]), fmaxf(redm[2], redm[3]));

  // ---- integer exp ----
  auto expi = [&](float xi) -> float {
    float xint = fmaxf(xi - m, clampv);       // clamp to 30*x0_int
    float q = xint / x0_int;                  // both negative -> q >= 0
    q = floorf(q);                            // q in [0, 30]
    float r = xint - x0_int * q;
    float z = r * (r + b_int) + c_int;
    int qi = (int)q;
    // 2^(30 - q) exactly: exponent bits (127 + 30 - q) << 23
    float p2 = __uint_as_float((unsigned)(157 - qi) << 23);
    return fmaxf(floorf(z * p2), 0.0f);
  };
  const float e0 = expi(xi0);
  const float e1 = expi(xi1);
  const float e2 = expi(xi2);
  const float e3 = expi(xi3);

  // ---- row sum ----
  float t = wave_reduce_sum((e0 + e1) + (e2 + e3));
  if ((tid & 63) == 0) reds[wave] = t;
  __syncthreads();
  t = (reds[0] + reds[1]) + (reds[2] + reds[3]);

  // ---- normalize & store ----
  const float rinv = 1.0f / t;                // one exact div per thread
  float4 o;
  o.x = e0 * rinv;
  o.y = e1 * rinv;
  o.z = e2 * rinv;
  o.w = e3 * rinv;
  reinterpret_cast<float4*>(out + (size_t)row * SROW)[tid] = o;
}

extern "C" void kernel_launch(void* const* d_in, const int* in_sizes, int n_in,
                              void* d_out, int out_size, void* d_ws, size_t ws_size,
                              hipStream_t stream) {
  const float* x      = (const float*)d_in[0];
  const float* scales = (const float*)d_in[1];
  float* out          = (float*)d_out;

  const int rows = in_sizes[0] / SROW;  // B*H*S = 98304
  const int H    = in_sizes[1];         // 12

  qint_softmax_kernel<<<dim3(rows), dim3(256), 0, stream>>>(x, scales, out, H);
}

// Round 2
// 131.239 us; speedup vs baseline: 1.3861x; 1.3861x over previous
//
#include <hip/hip_runtime.h>

// QIntSoftmax (I-BERT integer softmax), x: (8,12,1024,1024) f32 -> out f32.
// One wave (64 lanes) per row of 1024; 16 elements per lane; pure intra-wave
// shuffle reductions (no LDS, no barriers); per-element divisions replaced by
// reciprocal-multiplies (per-head constants still use exact IEEE div).

constexpr int SROW = 1024;
constexpr int ELEMS = 16;          // per lane (64 * 16 = 1024)
constexpr int ROWS_PER_BLOCK = 4;  // 4 waves per 256-thread block

typedef float floatx4 __attribute__((ext_vector_type(4)));

__global__ __launch_bounds__(256) void qint_softmax_kernel(
    const float* __restrict__ x, const float* __restrict__ scales,
    float* __restrict__ out, int H) {
  const int wave = threadIdx.x >> 6;
  const int lane = threadIdx.x & 63;
  const int row  = blockIdx.x * ROWS_PER_BLOCK + wave;  // row in [0, B*H*S)
  const int h = (row >> 10) % H;                        // S == 1024
  const float s = scales[h];

  // Per-head constants with exact IEEE division (bit-match the reference).
  const float x0_int = floorf(-0.6931f / s);
  const float b_int  = floorf((float)(0.96963238 / 0.35815147) / s);
  const float c_int  = floorf((float)(1.0 / 0.35815147) / (s * s));
  const float clampv = 30.0f * x0_int;   // N_BITS * x0_int (exact)
  const float inv_s  = 1.0f / s;         // once per thread
  const float inv_x0 = 1.0f / x0_int;    // once per thread

  const floatx4* __restrict__ px =
      reinterpret_cast<const floatx4*>(x + (size_t)row * SROW);
  floatx4* __restrict__ po =
      reinterpret_cast<floatx4*>(out + (size_t)row * SROW);

  // ---- load 16 elements, scale by 1/s ----
  float xv[ELEMS];
#pragma unroll
  for (int j = 0; j < 4; ++j) {
    floatx4 v = __builtin_nontemporal_load(px + (lane + 64 * j));
    xv[4 * j + 0] = v.x * inv_s;
    xv[4 * j + 1] = v.y * inv_s;
    xv[4 * j + 2] = v.z * inv_s;
    xv[4 * j + 3] = v.w * inv_s;
  }

  // ---- row max (tree + 6-step wave shuffle) ----
  float m0 = xv[0], m1 = xv[1];
#pragma unroll
  for (int j = 2; j < ELEMS; j += 2) {
    m0 = fmaxf(m0, xv[j]);
    m1 = fmaxf(m1, xv[j + 1]);
  }
  float m = fmaxf(m0, m1);
#pragma unroll
  for (int off = 32; off > 0; off >>= 1)
    m = fmaxf(m, __shfl_xor(m, off));

  // ---- integer exp + partial sum ----
  float t = 0.0f;
#pragma unroll
  for (int j = 0; j < ELEMS; ++j) {
    float xint = fmaxf(xv[j] - m, clampv);            // clamp to 30*x0_int
    float q = floorf(xint * inv_x0);                  // q in [0, 30]
    float r = xint - x0_int * q;
    float z = r * (r + b_int) + c_int;                // always > 0
    float p2 = __uint_as_float((unsigned)(157 - (int)q) << 23);  // 2^(30-q)
    float e = floorf(z * p2);
    xv[j] = e;
    t += e;
  }
#pragma unroll
  for (int off = 32; off > 0; off >>= 1)
    t += __shfl_xor(t, off);

  // ---- normalize & store ----
  const float rinv = 1.0f / t;
#pragma unroll
  for (int j = 0; j < 4; ++j) {
    floatx4 o;
    o.x = xv[4 * j + 0] * rinv;
    o.y = xv[4 * j + 1] * rinv;
    o.z = xv[4 * j + 2] * rinv;
    o.w = xv[4 * j + 3] * rinv;
    __builtin_nontemporal_store(o, po + (lane + 64 * j));
  }
}

extern "C" void kernel_launch(void* const* d_in, const int* in_sizes, int n_in,
                              void* d_out, int out_size, void* d_ws, size_t ws_size,
                              hipStream_t stream) {
  const float* x      = (const float*)d_in[0];
  const float* scales = (const float*)d_in[1];
  float* out          = (float*)d_out;

  const int rows = in_sizes[0] / SROW;  // B*H*S = 98304
  const int H    = in_sizes[1];         // 12

  qint_softmax_kernel<<<dim3(rows / ROWS_PER_BLOCK), dim3(256), 0, stream>>>(
      x, scales, out, H);
}